// Round 5
// baseline (314.474 us; speedup 1.0000x reference)
//
#include <hip/hip_runtime.h>
#include <math.h>

#define BATCH   128
#define VOCAB   128256
#define NCHUNK  4
#define CSIZE   32064           // VOCAB / NCHUNK
#define CVEC    (CSIZE / 4)     // 8016 float4 groups
#define T1      1024
#define NBKT    2048
#define CAP     2048            // power of two (bitonic pad limit)
#define KSEL    32
#define CWIDTH  (NCHUNK * KSEL) // 128 candidates per row
#define T2      128
#define TAILTID 848             // CVEC - 7*T1

// Monotone (order-preserving) encoding of float -> uint32.
__device__ __forceinline__ unsigned fenc(float f) {
    unsigned u = __float_as_uint(f);
    return (u & 0x80000000u) ? ~u : (u | 0x80000000u);
}

// Penalized logit, replicating reference op order in f32 with explicit
// separately-rounded ops (no FMA contraction -> matches numpy elementwise).
__device__ __forceinline__ float penalize(float l, float cnt, float pf,
                                          float rep, float freq, float pres) {
    float occ   = __fsub_rn(cnt, fmaxf(__fsub_rn(cnt, 1.0f), 0.0f));
    float ru    = __fadd_rn(occ, pf);
    float rmask = __fsub_rn(ru, fmaxf(__fsub_rn(ru, 1.0f), 0.0f));
    float pos   = fmaxf(l, 0.0f);
    float neg   = fminf(l, 0.0f);
    float pen   = __fadd_rn(__fdiv_rn(pos, rep), __fmul_rn(neg, rep));
    float p     = __fadd_rn(l, __fmul_rn(rmask, __fsub_rn(pen, l)));
    p = __fsub_rn(p, __fmul_rn(freq, cnt));
    p = __fsub_rn(p, __fmul_rn(pres, occ));
    return p;
}

// Load 4 mask flags for group i as packed bytes in one unsigned.
// mtype: 0 = packed bytes (bool/uint8), 1 = int32 {0,1}, 2 = float32.
__device__ __forceinline__ unsigned ldmask(const void* pm, long base, int i, int mtype) {
    if (mtype == 0) {
        return ((const unsigned*)((const unsigned char*)pm + base))[i];
    } else if (mtype == 1) {
        int4 m = ((const int4*)((const int*)pm + base))[i];
        return (m.x ? 1u : 0u) | (m.y ? 0x100u : 0u) | (m.z ? 0x10000u : 0u) | (m.w ? 0x1000000u : 0u);
    } else {
        float4 f = ((const float4*)((const float*)pm + base))[i];
        return ((f.x != 0.f) ? 1u : 0u) | ((f.y != 0.f) ? 0x100u : 0u) |
               ((f.z != 0.f) ? 0x10000u : 0u) | ((f.w != 0.f) ? 0x1000000u : 0u);
    }
}

__global__ __launch_bounds__(T1, 8) void sampler_k1(
    const float* __restrict__ logits, const float* __restrict__ counts,
    const void* __restrict__ pmask,
    const float* __restrict__ temperature, const float* __restrict__ presence,
    const float* __restrict__ frequency, const float* __restrict__ repetition,
    float* __restrict__ g_topv, int* __restrict__ g_topi,
    float* __restrict__ g_gval, int* __restrict__ g_gidx)
{
    const int b   = blockIdx.x >> 2;
    const int c   = blockIdx.x & 3;
    const int tid = threadIdx.x;
    const long base = (long)b * VOCAB + (long)c * CSIZE;

    __shared__ unsigned hist[NBKT];
    __shared__ float    cv[CAP];
    __shared__ int      ci[CAP];
    __shared__ unsigned ccnt;
    __shared__ int      s_tb;
    __shared__ int      s_m0, s_mf;
    __shared__ float    wrv[16];
    __shared__ int      wri[16];

    for (int i = tid; i < NBKT; i += T1) hist[i] = 0;
    if (tid == 0) { ccnt = 0; s_m0 = 1; s_mf = 1; }
    __syncthreads();

    // ---- mask dtype detect: every block scans the SAME first 4096 words ----
    {
        const unsigned* w = (const unsigned*)pmask;
        int a01 = 1, af = 1;
        for (int i = tid; i < 4096; i += T1) {
            unsigned x = w[i];
            if (!(x == 0u || x == 1u)) a01 = 0;
            if (!(x == 0u || x == 0x3F800000u)) af = 0;
        }
        if (!a01) atomicAnd(&s_m0, 0);
        if (!af)  atomicAnd(&s_mf, 0);
    }
    __syncthreads();
    const int mtype = s_m0 ? 1 : (s_mf ? 2 : 0);

    const float temp = temperature[b];
    const float teff = (temp < 1e-5f) ? 1.0f : temp;
    const float pres = presence[b];
    const float freq = frequency[b];
    const float rep  = repetition[b];

    const float4* l4 = (const float4*)(logits + base);
    const float4* c4 = (const float4*)(counts + base);

    float gmax = -INFINITY;
    int   gidx = 0x7fffffff;

    // ---- scan 1: histogram + greedy argmax (4x batched loads for MLP) ----
#define PROC1(Lv, Cv, Mv, I0) do {                                             \
        float le_[4] = {(Lv).x, (Lv).y, (Lv).z, (Lv).w};                       \
        float ce_[4] = {(Cv).x, (Cv).y, (Cv).z, (Cv).w};                       \
        _Pragma("unroll")                                                      \
        for (int e_ = 0; e_ < 4; ++e_) {                                       \
            float pf_ = (((Mv) >> (8 * e_)) & 0xffu) ? 1.0f : 0.0f;            \
            float p_  = penalize(le_[e_], ce_[e_], pf_, rep, freq, pres);      \
            int idx_  = (I0) * 4 + e_;                                         \
            if (p_ > gmax) { gmax = p_; gidx = idx_; }                         \
            float v_ = __fdiv_rn(p_, teff);                                    \
            atomicAdd(&hist[fenc(v_) >> 21], 1u);                              \
        }                                                                      \
    } while (0)

    {
        // batch A: groups k=0..3 (always in range: tid+3*T1 <= 4095 < 8016)
        float4 L0 = l4[tid],            L1 = l4[tid + T1];
        float4 L2 = l4[tid + 2 * T1],   L3 = l4[tid + 3 * T1];
        float4 C0 = c4[tid],            C1 = c4[tid + T1];
        float4 C2 = c4[tid + 2 * T1],   C3 = c4[tid + 3 * T1];
        unsigned M0 = ldmask(pmask, base, tid,          mtype);
        unsigned M1 = ldmask(pmask, base, tid + T1,     mtype);
        unsigned M2 = ldmask(pmask, base, tid + 2 * T1, mtype);
        unsigned M3 = ldmask(pmask, base, tid + 3 * T1, mtype);
        PROC1(L0, C0, M0, tid);
        PROC1(L1, C1, M1, tid + T1);
        PROC1(L2, C2, M2, tid + 2 * T1);
        PROC1(L3, C3, M3, tid + 3 * T1);
    }
    {
        // batch B: groups k=4..6 (tid+6*T1 <= 7167 < 8016)
        float4 L0 = l4[tid + 4 * T1], L1 = l4[tid + 5 * T1], L2 = l4[tid + 6 * T1];
        float4 C0 = c4[tid + 4 * T1], C1 = c4[tid + 5 * T1], C2 = c4[tid + 6 * T1];
        unsigned M0 = ldmask(pmask, base, tid + 4 * T1, mtype);
        unsigned M1 = ldmask(pmask, base, tid + 5 * T1, mtype);
        unsigned M2 = ldmask(pmask, base, tid + 6 * T1, mtype);
        PROC1(L0, C0, M0, tid + 4 * T1);
        PROC1(L1, C1, M1, tid + 5 * T1);
        PROC1(L2, C2, M2, tid + 6 * T1);
    }
    if (tid < TAILTID) {
        // tail: group k=7
        float4 L0 = l4[tid + 7 * T1];
        float4 C0 = c4[tid + 7 * T1];
        unsigned M0 = ldmask(pmask, base, tid + 7 * T1, mtype);
        PROC1(L0, C0, M0, tid + 7 * T1);
    }
#undef PROC1

    // ---- greedy reduce: wave shuffle, then 16-entry merge ----
    for (int off = 32; off > 0; off >>= 1) {
        float ov = __shfl_down(gmax, off);
        int   oi = __shfl_down(gidx, off);
        if (ov > gmax || (ov == gmax && oi < gidx)) { gmax = ov; gidx = oi; }
    }
    if ((tid & 63) == 0) { wrv[tid >> 6] = gmax; wri[tid >> 6] = gidx; }
    __syncthreads();   // hist complete + wave partials visible
    if (tid == 0) {
        float bv = wrv[0]; int bi = wri[0];
        for (int w2 = 1; w2 < 16; ++w2) {
            if (wrv[w2] > bv || (wrv[w2] == bv && wri[w2] < bi)) { bv = wrv[w2]; bi = wri[w2]; }
        }
        g_gval[blockIdx.x] = bv;
        g_gidx[blockIdx.x] = c * CSIZE + bi;
    }

    // ---- threshold bucket (parallel suffix-count in wave 0) ----
    if (tid < 64) {
        const int gb = tid * 32;
        unsigned gs = 0;
#pragma unroll
        for (int k = 0; k < 32; ++k) gs += hist[gb + k];
        unsigned suf = gs;
#pragma unroll
        for (int off = 1; off < 64; off <<= 1) {
            unsigned o = __shfl_down(suf, off);
            if (tid + off < 64) suf += o;
        }
        unsigned sufn = __shfl_down(suf, 1);
        if (tid == 63) sufn = 0;
        if (suf >= (unsigned)KSEL && sufn < (unsigned)KSEL) {
            unsigned acc = sufn; int tb = gb;
            for (int q = gb + 31; q >= gb; --q) {
                acc += hist[q];
                if (acc >= (unsigned)KSEL) { tb = q; break; }
            }
            s_tb = tb;
        }
    }
    __syncthreads();
    const unsigned thr = ((unsigned)s_tb) << 21;

    // ---- scan 2: collect candidates >= threshold (4x batched) ----
#define PROC2(Lv, Cv, Mv, I0) do {                                             \
        float le_[4] = {(Lv).x, (Lv).y, (Lv).z, (Lv).w};                       \
        float ce_[4] = {(Cv).x, (Cv).y, (Cv).z, (Cv).w};                       \
        _Pragma("unroll")                                                      \
        for (int e_ = 0; e_ < 4; ++e_) {                                       \
            float pf_ = (((Mv) >> (8 * e_)) & 0xffu) ? 1.0f : 0.0f;            \
            float p_  = penalize(le_[e_], ce_[e_], pf_, rep, freq, pres);      \
            float v_  = __fdiv_rn(p_, teff);                                   \
            if (fenc(v_) >= thr) {                                             \
                unsigned pos_ = atomicAdd(&ccnt, 1u);                          \
                if (pos_ < CAP) { cv[pos_] = v_; ci[pos_] = (I0) * 4 + e_; }   \
            }                                                                  \
        }                                                                      \
    } while (0)

    {
        float4 L0 = l4[tid],            L1 = l4[tid + T1];
        float4 L2 = l4[tid + 2 * T1],   L3 = l4[tid + 3 * T1];
        float4 C0 = c4[tid],            C1 = c4[tid + T1];
        float4 C2 = c4[tid + 2 * T1],   C3 = c4[tid + 3 * T1];
        unsigned M0 = ldmask(pmask, base, tid,          mtype);
        unsigned M1 = ldmask(pmask, base, tid + T1,     mtype);
        unsigned M2 = ldmask(pmask, base, tid + 2 * T1, mtype);
        unsigned M3 = ldmask(pmask, base, tid + 3 * T1, mtype);
        PROC2(L0, C0, M0, tid);
        PROC2(L1, C1, M1, tid + T1);
        PROC2(L2, C2, M2, tid + 2 * T1);
        PROC2(L3, C3, M3, tid + 3 * T1);
    }
    {
        float4 L0 = l4[tid + 4 * T1], L1 = l4[tid + 5 * T1], L2 = l4[tid + 6 * T1];
        float4 C0 = c4[tid + 4 * T1], C1 = c4[tid + 5 * T1], C2 = c4[tid + 6 * T1];
        unsigned M0 = ldmask(pmask, base, tid + 4 * T1, mtype);
        unsigned M1 = ldmask(pmask, base, tid + 5 * T1, mtype);
        unsigned M2 = ldmask(pmask, base, tid + 6 * T1, mtype);
        PROC2(L0, C0, M0, tid + 4 * T1);
        PROC2(L1, C1, M1, tid + 5 * T1);
        PROC2(L2, C2, M2, tid + 6 * T1);
    }
    if (tid < TAILTID) {
        float4 L0 = l4[tid + 7 * T1];
        float4 C0 = c4[tid + 7 * T1];
        unsigned M0 = ldmask(pmask, base, tid + 7 * T1, mtype);
        PROC2(L0, C0, M0, tid + 7 * T1);
    }
#undef PROC2
    __syncthreads();

    unsigned m = ccnt;
    if (m > CAP) m = CAP;
    unsigned P = KSEL;
    while (P < m) P <<= 1;
    for (unsigned s = m + tid; s < P; s += T1) { cv[s] = -INFINITY; ci[s] = 0x7fffffff; }
    __syncthreads();

    // ---- bitonic sort, best-first: key = (value desc, index asc) ----
    for (unsigned k = 2; k <= P; k <<= 1) {
        for (unsigned j = k >> 1; j > 0; j >>= 1) {
            for (unsigned s = tid; s < P; s += T1) {
                unsigned x = s ^ j;
                if (x > s) {
                    float av = cv[s], bv = cv[x];
                    int   ai = ci[s], bi = ci[x];
                    bool xBetter = (bv > av) || (bv == av && bi < ai);
                    bool sBetter = (av > bv) || (av == bv && ai < bi);
                    bool doSwap  = ((s & k) == 0) ? xBetter : sBetter;
                    if (doSwap) { cv[s] = bv; cv[x] = av; ci[s] = bi; ci[x] = ai; }
                }
            }
            __syncthreads();
        }
    }

    if (tid < KSEL) {
        int o = blockIdx.x * KSEL + tid;
        g_topv[o] = cv[tid];
        g_topi[o] = c * CSIZE + ci[tid];
    }
}

__global__ __launch_bounds__(T2) void sampler_k2(
    const float* __restrict__ g_topv, const int* __restrict__ g_topi,
    const float* __restrict__ g_gval, const int* __restrict__ g_gidx,
    const float* __restrict__ temperature, const int* __restrict__ topk,
    const float* __restrict__ topp, const float* __restrict__ qs,
    float* __restrict__ out)
{
    const int b = blockIdx.x;
    const int j = threadIdx.x;

    __shared__ int   ix[T2];
    __shared__ float sv[T2];
    __shared__ float cum[T2];
    __shared__ float red[T2];
    __shared__ int   redi[T2];

    float val = g_topv[b * CWIDTH + j];
    int   idx = g_topi[b * CWIDTH + j];
    ix[j] = idx;

    // ---- softmax #1 ----
    red[j] = val; __syncthreads();
    for (int s = T2 / 2; s > 0; s >>= 1) {
        if (j < s) red[j] = fmaxf(red[j], red[j + s]);
        __syncthreads();
    }
    float m1 = red[0]; __syncthreads();
    float e = expf(__fsub_rn(val, m1));
    red[j] = e; __syncthreads();
    for (int s = T2 / 2; s > 0; s >>= 1) {
        if (j < s) red[j] = __fadd_rn(red[j], red[j + s]);
        __syncthreads();
    }
    float s1 = red[0]; __syncthreads();
    float prob = __fdiv_rn(e, s1);
    sv[j] = prob;
    __syncthreads();

    // ---- sort probs ascending (bitonic over 128) ----
    for (unsigned k = 2; k <= (unsigned)T2; k <<= 1) {
        for (unsigned jj = k >> 1; jj > 0; jj >>= 1) {
            unsigned x = (unsigned)j ^ jj;
            if (x > (unsigned)j) {
                float a = sv[j], bb = sv[x];
                bool sw = (((unsigned)j & k) == 0) ? (a > bb) : (a < bb);
                if (sw) { sv[j] = bb; sv[x] = a; }
            }
            __syncthreads();
        }
    }

    // ---- inclusive cumsum (serial: matches np.cumsum rounding) ----
    if (j == 0) {
        float a = 0.0f;
        for (int t = 0; t < T2; ++t) { a = __fadd_rn(a, sv[t]); cum[t] = a; }
    }
    __syncthreads();

    const int   k_row = topk[b];
    const float p_row = topp[b];
    int count_k = CWIDTH - k_row;
    count_k = min(max(count_k, 0), CWIDTH - 1);
    float cutoff_k = sv[count_k];
    if (k_row <= 0 || k_row >= VOCAB) cutoff_k = -INFINITY;

    float lim = __fsub_rn(1.0f, p_row);
    bool mk = (j < CWIDTH - 1) && (cum[j] <= lim);
    redi[j] = mk ? 1 : 0; __syncthreads();
    for (int s = T2 / 2; s > 0; s >>= 1) {
        if (j < s) redi[j] += redi[j + s];
        __syncthreads();
    }
    int count_p = redi[0]; __syncthreads();
    float cutoff_p = sv[count_p];

    float f = val;
    if (prob < cutoff_k) f = -INFINITY;
    if (prob < cutoff_p) f = -INFINITY;

    // ---- softmax #2 ----
    red[j] = f; __syncthreads();
    for (int s = T2 / 2; s > 0; s >>= 1) {
        if (j < s) red[j] = fmaxf(red[j], red[j + s]);
        __syncthreads();
    }
    float m2 = red[0]; __syncthreads();
    float e2 = (f == -INFINITY) ? 0.0f : expf(__fsub_rn(f, m2));
    red[j] = e2; __syncthreads();
    for (int s = T2 / 2; s > 0; s >>= 1) {
        if (j < s) red[j] = __fadd_rn(red[j], red[j + s]);
        __syncthreads();
    }
    float s2 = red[0]; __syncthreads();
    float pf = __fdiv_rn(e2, s2);
    out[BATCH + b * CWIDTH + j] = pf;

    // ---- argmax(prob / q), first-index tie-break ----
    float q = qs[(long)b * VOCAB + idx];
    float ratio = __fdiv_rn(pf, q);
    red[j] = ratio; redi[j] = j;
    __syncthreads();
    for (int s = T2 / 2; s > 0; s >>= 1) {
        if (j < s) {
            float o = red[j + s]; int oi = redi[j + s];
            if (o > red[j] || (o == red[j] && oi < redi[j])) { red[j] = o; redi[j] = oi; }
        }
        __syncthreads();
    }

    if (j == 0) {
        float bvv = g_gval[b * NCHUNK]; int bii = g_gidx[b * NCHUNK];
        for (int c2 = 1; c2 < NCHUNK; ++c2) {
            float w = g_gval[b * NCHUNK + c2]; int wi = g_gidx[b * NCHUNK + c2];
            if (w > bvv || (w == bvv && wi < bii)) { bvv = w; bii = wi; }
        }
        int token = ix[redi[0]];
        float tmp = temperature[b];
        int samp = (tmp < 1e-5f) ? bii : token;
        out[b] = (float)samp;
    }
}

extern "C" void kernel_launch(void* const* d_in, const int* in_sizes, int n_in,
                              void* d_out, int out_size, void* d_ws, size_t ws_size,
                              hipStream_t stream) {
    const float* logits = (const float*)d_in[0];
    const float* temp   = (const float*)d_in[1];
    const int*   topk   = (const int*)d_in[2];
    const float* topp   = (const float*)d_in[3];
    const float* counts = (const float*)d_in[4];
    const void*  pmask  = d_in[5];
    const float* pres   = (const float*)d_in[6];
    const float* freq   = (const float*)d_in[7];
    const float* rep    = (const float*)d_in[8];
    const float* qs     = (const float*)d_in[9];
    float* out = (float*)d_out;

    float* g_topv = (float*)d_ws;                        // BATCH*CWIDTH
    int*   g_topi = (int*)(g_topv + BATCH * CWIDTH);     // BATCH*CWIDTH
    float* g_gval = (float*)(g_topi + BATCH * CWIDTH);   // BATCH*NCHUNK
    int*   g_gidx = (int*)(g_gval + BATCH * NCHUNK);     // BATCH*NCHUNK

    sampler_k1<<<BATCH * NCHUNK, T1, 0, stream>>>(
        logits, counts, pmask, temp, pres, freq, rep,
        g_topv, g_topi, g_gval, g_gidx);

    sampler_k2<<<BATCH, T2, 0, stream>>>(
        g_topv, g_topi, g_gval, g_gidx, temp, topk, topp, qs, out);
}

// Round 6
// 274.733 us; speedup vs baseline: 1.1447x; 1.1447x over previous
//
#include <hip/hip_runtime.h>
#include <math.h>

#define BATCH   128
#define VOCAB   128256
#define NCHUNK  4
#define CSIZE   32064           // VOCAB / NCHUNK
#define CVEC    (CSIZE / 4)     // 8016 float4 groups
#define T1      1024
#define NBKT    2048
#define CAP     2048            // power of two (bitonic pad limit)
#define KSEL    32
#define CWIDTH  (NCHUNK * KSEL) // 128 candidates per row
#define T2      128
#define TAILTID 848             // CVEC - 7*T1

// Monotone (order-preserving) encoding of float -> uint32.
__device__ __forceinline__ unsigned fenc(float f) {
    unsigned u = __float_as_uint(f);
    return (u & 0x80000000u) ? ~u : (u | 0x80000000u);
}

// Penalized logit, replicating reference op order in f32 with explicit
// separately-rounded ops (no FMA contraction -> matches numpy elementwise).
__device__ __forceinline__ float penalize(float l, float cnt, float pf,
                                          float rep, float freq, float pres) {
    float occ   = __fsub_rn(cnt, fmaxf(__fsub_rn(cnt, 1.0f), 0.0f));
    float ru    = __fadd_rn(occ, pf);
    float rmask = __fsub_rn(ru, fmaxf(__fsub_rn(ru, 1.0f), 0.0f));
    float pos   = fmaxf(l, 0.0f);
    float neg   = fminf(l, 0.0f);
    float pen   = __fadd_rn(__fdiv_rn(pos, rep), __fmul_rn(neg, rep));
    float p     = __fadd_rn(l, __fmul_rn(rmask, __fsub_rn(pen, l)));
    p = __fsub_rn(p, __fmul_rn(freq, cnt));
    p = __fsub_rn(p, __fmul_rn(pres, occ));
    return p;
}

// Load 4 mask flags for group i as packed bytes in one unsigned.
// mtype: 0 = packed bytes (bool/uint8), 1 = int32 {0,1}, 2 = float32.
__device__ __forceinline__ unsigned ldmask(const void* pm, long base, int i, int mtype) {
    if (mtype == 0) {
        return ((const unsigned*)((const unsigned char*)pm + base))[i];
    } else if (mtype == 1) {
        int4 m = ((const int4*)((const int*)pm + base))[i];
        return (m.x ? 1u : 0u) | (m.y ? 0x100u : 0u) | (m.z ? 0x10000u : 0u) | (m.w ? 0x1000000u : 0u);
    } else {
        float4 f = ((const float4*)((const float*)pm + base))[i];
        return ((f.x != 0.f) ? 1u : 0u) | ((f.y != 0.f) ? 0x100u : 0u) |
               ((f.z != 0.f) ? 0x10000u : 0u) | ((f.w != 0.f) ? 0x1000000u : 0u);
    }
}

__global__ __launch_bounds__(T1, 4) void sampler_k1(
    const float* __restrict__ logits, const float* __restrict__ counts,
    const void* __restrict__ pmask,
    const float* __restrict__ temperature, const float* __restrict__ presence,
    const float* __restrict__ frequency, const float* __restrict__ repetition,
    float* __restrict__ g_topv, int* __restrict__ g_topi,
    float* __restrict__ g_gval, int* __restrict__ g_gidx)
{
    const int b   = blockIdx.x >> 2;
    const int c   = blockIdx.x & 3;
    const int tid = threadIdx.x;
    const long base = (long)b * VOCAB + (long)c * CSIZE;

    __shared__ unsigned hist[NBKT];
    __shared__ float    cv[CAP];
    __shared__ int      ci[CAP];
    __shared__ unsigned ccnt;
    __shared__ int      s_tb;
    __shared__ int      s_m0, s_mf;
    __shared__ float    wrv[16];
    __shared__ int      wri[16];

    for (int i = tid; i < NBKT; i += T1) hist[i] = 0;
    if (tid == 0) { ccnt = 0; s_m0 = 1; s_mf = 1; }
    __syncthreads();

    // ---- mask dtype detect: every block scans the SAME first 4096 words ----
    {
        const unsigned* w = (const unsigned*)pmask;
        int a01 = 1, af = 1;
        for (int i = tid; i < 4096; i += T1) {
            unsigned x = w[i];
            if (!(x == 0u || x == 1u)) a01 = 0;
            if (!(x == 0u || x == 0x3F800000u)) af = 0;
        }
        if (!a01) atomicAnd(&s_m0, 0);
        if (!af)  atomicAnd(&s_mf, 0);
    }
    __syncthreads();
    const int mtype = s_m0 ? 1 : (s_mf ? 2 : 0);

    const float temp = temperature[b];
    const float teff = (temp < 1e-5f) ? 1.0f : temp;
    const float pres = presence[b];
    const float freq = frequency[b];
    const float rep  = repetition[b];

    const float4* l4 = (const float4*)(logits + base);
    const float4* c4 = (const float4*)(counts + base);

    float gmax = -INFINITY;
    int   gidx = 0x7fffffff;

    const bool tail = tid < TAILTID;

    // Scaled values kept register-resident (explicit components, no arrays).
    float4 v0, v1, v2, v3, v4, v5, v6, v7;
    v7.x = v7.y = v7.z = v7.w = 0.0f;

// Process one float4 group: penalty, greedy track, scale, histogram, keep v.
#define PROC1(Lv, Cv, Mv, Vv, I0) do {                                          \
        float p_;                                                               \
        p_ = penalize((Lv).x, (Cv).x, ((Mv) & 0x000000ffu) ? 1.0f : 0.0f,       \
                      rep, freq, pres);                                         \
        if (p_ > gmax) { gmax = p_; gidx = (I0) * 4 + 0; }                      \
        (Vv).x = __fdiv_rn(p_, teff);                                           \
        atomicAdd(&hist[fenc((Vv).x) >> 21], 1u);                               \
        p_ = penalize((Lv).y, (Cv).y, ((Mv) & 0x0000ff00u) ? 1.0f : 0.0f,       \
                      rep, freq, pres);                                         \
        if (p_ > gmax) { gmax = p_; gidx = (I0) * 4 + 1; }                      \
        (Vv).y = __fdiv_rn(p_, teff);                                           \
        atomicAdd(&hist[fenc((Vv).y) >> 21], 1u);                               \
        p_ = penalize((Lv).z, (Cv).z, ((Mv) & 0x00ff0000u) ? 1.0f : 0.0f,       \
                      rep, freq, pres);                                         \
        if (p_ > gmax) { gmax = p_; gidx = (I0) * 4 + 2; }                      \
        (Vv).z = __fdiv_rn(p_, teff);                                           \
        atomicAdd(&hist[fenc((Vv).z) >> 21], 1u);                               \
        p_ = penalize((Lv).w, (Cv).w, ((Mv) & 0xff000000u) ? 1.0f : 0.0f,       \
                      rep, freq, pres);                                         \
        if (p_ > gmax) { gmax = p_; gidx = (I0) * 4 + 3; }                      \
        (Vv).w = __fdiv_rn(p_, teff);                                           \
        atomicAdd(&hist[fenc((Vv).w) >> 21], 1u);                               \
    } while (0)

    {
        // batch A: groups k=0..3 (tid+3*T1 <= 4095 < 8016)
        float4 L0 = l4[tid],          L1 = l4[tid + T1];
        float4 L2 = l4[tid + 2 * T1], L3 = l4[tid + 3 * T1];
        float4 C0 = c4[tid],          C1 = c4[tid + T1];
        float4 C2 = c4[tid + 2 * T1], C3 = c4[tid + 3 * T1];
        unsigned M0 = ldmask(pmask, base, tid,          mtype);
        unsigned M1 = ldmask(pmask, base, tid + T1,     mtype);
        unsigned M2 = ldmask(pmask, base, tid + 2 * T1, mtype);
        unsigned M3 = ldmask(pmask, base, tid + 3 * T1, mtype);
        PROC1(L0, C0, M0, v0, tid);
        PROC1(L1, C1, M1, v1, tid + T1);
        PROC1(L2, C2, M2, v2, tid + 2 * T1);
        PROC1(L3, C3, M3, v3, tid + 3 * T1);
    }
    {
        // batch B: groups k=4..6 always; k=7 only if tail
        float4 L4 = l4[tid + 4 * T1], L5 = l4[tid + 5 * T1], L6 = l4[tid + 6 * T1];
        float4 C4 = c4[tid + 4 * T1], C5 = c4[tid + 5 * T1], C6 = c4[tid + 6 * T1];
        unsigned M4 = ldmask(pmask, base, tid + 4 * T1, mtype);
        unsigned M5 = ldmask(pmask, base, tid + 5 * T1, mtype);
        unsigned M6 = ldmask(pmask, base, tid + 6 * T1, mtype);
        float4 L7, C7; unsigned M7 = 0;
        if (tail) {
            L7 = l4[tid + 7 * T1];
            C7 = c4[tid + 7 * T1];
            M7 = ldmask(pmask, base, tid + 7 * T1, mtype);
        }
        PROC1(L4, C4, M4, v4, tid + 4 * T1);
        PROC1(L5, C5, M5, v5, tid + 5 * T1);
        PROC1(L6, C6, M6, v6, tid + 6 * T1);
        if (tail) PROC1(L7, C7, M7, v7, tid + 7 * T1);
    }
#undef PROC1

    // ---- greedy reduce: wave shuffle, then 16-entry merge ----
    for (int off = 32; off > 0; off >>= 1) {
        float ov = __shfl_down(gmax, off);
        int   oi = __shfl_down(gidx, off);
        if (ov > gmax || (ov == gmax && oi < gidx)) { gmax = ov; gidx = oi; }
    }
    if ((tid & 63) == 0) { wrv[tid >> 6] = gmax; wri[tid >> 6] = gidx; }
    __syncthreads();   // hist complete + wave partials visible
    if (tid == 0) {
        float bv = wrv[0]; int bi = wri[0];
        for (int w2 = 1; w2 < 16; ++w2) {
            if (wrv[w2] > bv || (wrv[w2] == bv && wri[w2] < bi)) { bv = wrv[w2]; bi = wri[w2]; }
        }
        g_gval[blockIdx.x] = bv;
        g_gidx[blockIdx.x] = c * CSIZE + bi;
    }

    // ---- threshold bucket (parallel suffix-count in wave 0) ----
    if (tid < 64) {
        const int gb = tid * 32;
        unsigned gs = 0;
#pragma unroll
        for (int k = 0; k < 32; ++k) gs += hist[gb + k];
        unsigned suf = gs;
#pragma unroll
        for (int off = 1; off < 64; off <<= 1) {
            unsigned o = __shfl_down(suf, off);
            if (tid + off < 64) suf += o;
        }
        unsigned sufn = __shfl_down(suf, 1);
        if (tid == 63) sufn = 0;
        if (suf >= (unsigned)KSEL && sufn < (unsigned)KSEL) {
            unsigned acc = sufn; int tb = gb;
            for (int q = gb + 31; q >= gb; --q) {
                acc += hist[q];
                if (acc >= (unsigned)KSEL) { tb = q; break; }
            }
            s_tb = tb;
        }
    }
    __syncthreads();
    const unsigned thr = ((unsigned)s_tb) << 21;

    // ---- collect candidates >= threshold from REGISTERS (no reloads) ----
#define COLL(Vv, I0) do {                                                       \
        if (fenc((Vv).x) >= thr) {                                              \
            unsigned pos_ = atomicAdd(&ccnt, 1u);                               \
            if (pos_ < CAP) { cv[pos_] = (Vv).x; ci[pos_] = (I0) * 4 + 0; }     \
        }                                                                       \
        if (fenc((Vv).y) >= thr) {                                              \
            unsigned pos_ = atomicAdd(&ccnt, 1u);                               \
            if (pos_ < CAP) { cv[pos_] = (Vv).y; ci[pos_] = (I0) * 4 + 1; }     \
        }                                                                       \
        if (fenc((Vv).z) >= thr) {                                              \
            unsigned pos_ = atomicAdd(&ccnt, 1u);                               \
            if (pos_ < CAP) { cv[pos_] = (Vv).z; ci[pos_] = (I0) * 4 + 2; }     \
        }                                                                       \
        if (fenc((Vv).w) >= thr) {                                              \
            unsigned pos_ = atomicAdd(&ccnt, 1u);                               \
            if (pos_ < CAP) { cv[pos_] = (Vv).w; ci[pos_] = (I0) * 4 + 3; }     \
        }                                                                       \
    } while (0)

    COLL(v0, tid);
    COLL(v1, tid + T1);
    COLL(v2, tid + 2 * T1);
    COLL(v3, tid + 3 * T1);
    COLL(v4, tid + 4 * T1);
    COLL(v5, tid + 5 * T1);
    COLL(v6, tid + 6 * T1);
    if (tail) COLL(v7, tid + 7 * T1);
#undef COLL
    __syncthreads();

    unsigned m = ccnt;
    if (m > CAP) m = CAP;
    unsigned P = KSEL;
    while (P < m) P <<= 1;
    for (unsigned s = m + tid; s < P; s += T1) { cv[s] = -INFINITY; ci[s] = 0x7fffffff; }
    __syncthreads();

    // ---- bitonic sort, best-first: key = (value desc, index asc) ----
    for (unsigned k = 2; k <= P; k <<= 1) {
        for (unsigned j = k >> 1; j > 0; j >>= 1) {
            for (unsigned s = tid; s < P; s += T1) {
                unsigned x = s ^ j;
                if (x > s) {
                    float av = cv[s], bv = cv[x];
                    int   ai = ci[s], bi = ci[x];
                    bool xBetter = (bv > av) || (bv == av && bi < ai);
                    bool sBetter = (av > bv) || (av == bv && ai < bi);
                    bool doSwap  = ((s & k) == 0) ? xBetter : sBetter;
                    if (doSwap) { cv[s] = bv; cv[x] = av; ci[s] = bi; ci[x] = ai; }
                }
            }
            __syncthreads();
        }
    }

    if (tid < KSEL) {
        int o = blockIdx.x * KSEL + tid;
        g_topv[o] = cv[tid];
        g_topi[o] = c * CSIZE + ci[tid];
    }
}

__global__ __launch_bounds__(T2) void sampler_k2(
    const float* __restrict__ g_topv, const int* __restrict__ g_topi,
    const float* __restrict__ g_gval, const int* __restrict__ g_gidx,
    const float* __restrict__ temperature, const int* __restrict__ topk,
    const float* __restrict__ topp, const float* __restrict__ qs,
    float* __restrict__ out)
{
    const int b = blockIdx.x;
    const int j = threadIdx.x;

    __shared__ int   ix[T2];
    __shared__ float sv[T2];
    __shared__ float cum[T2];
    __shared__ float red[T2];
    __shared__ int   redi[T2];

    float val = g_topv[b * CWIDTH + j];
    int   idx = g_topi[b * CWIDTH + j];
    ix[j] = idx;

    // ---- softmax #1 ----
    red[j] = val; __syncthreads();
    for (int s = T2 / 2; s > 0; s >>= 1) {
        if (j < s) red[j] = fmaxf(red[j], red[j + s]);
        __syncthreads();
    }
    float m1 = red[0]; __syncthreads();
    float e = expf(__fsub_rn(val, m1));
    red[j] = e; __syncthreads();
    for (int s = T2 / 2; s > 0; s >>= 1) {
        if (j < s) red[j] = __fadd_rn(red[j], red[j + s]);
        __syncthreads();
    }
    float s1 = red[0]; __syncthreads();
    float prob = __fdiv_rn(e, s1);
    sv[j] = prob;
    __syncthreads();

    // ---- sort probs ascending (bitonic over 128) ----
    for (unsigned k = 2; k <= (unsigned)T2; k <<= 1) {
        for (unsigned jj = k >> 1; jj > 0; jj >>= 1) {
            unsigned x = (unsigned)j ^ jj;
            if (x > (unsigned)j) {
                float a = sv[j], bb = sv[x];
                bool sw = (((unsigned)j & k) == 0) ? (a > bb) : (a < bb);
                if (sw) { sv[j] = bb; sv[x] = a; }
            }
            __syncthreads();
        }
    }

    // ---- inclusive cumsum (serial: matches np.cumsum rounding) ----
    if (j == 0) {
        float a = 0.0f;
        for (int t = 0; t < T2; ++t) { a = __fadd_rn(a, sv[t]); cum[t] = a; }
    }
    __syncthreads();

    const int   k_row = topk[b];
    const float p_row = topp[b];
    int count_k = CWIDTH - k_row;
    count_k = min(max(count_k, 0), CWIDTH - 1);
    float cutoff_k = sv[count_k];
    if (k_row <= 0 || k_row >= VOCAB) cutoff_k = -INFINITY;

    float lim = __fsub_rn(1.0f, p_row);
    bool mk = (j < CWIDTH - 1) && (cum[j] <= lim);
    redi[j] = mk ? 1 : 0; __syncthreads();
    for (int s = T2 / 2; s > 0; s >>= 1) {
        if (j < s) redi[j] += redi[j + s];
        __syncthreads();
    }
    int count_p = redi[0]; __syncthreads();
    float cutoff_p = sv[count_p];

    float f = val;
    if (prob < cutoff_k) f = -INFINITY;
    if (prob < cutoff_p) f = -INFINITY;

    // ---- softmax #2 ----
    red[j] = f; __syncthreads();
    for (int s = T2 / 2; s > 0; s >>= 1) {
        if (j < s) red[j] = fmaxf(red[j], red[j + s]);
        __syncthreads();
    }
    float m2 = red[0]; __syncthreads();
    float e2 = (f == -INFINITY) ? 0.0f : expf(__fsub_rn(f, m2));
    red[j] = e2; __syncthreads();
    for (int s = T2 / 2; s > 0; s >>= 1) {
        if (j < s) red[j] = __fadd_rn(red[j], red[j + s]);
        __syncthreads();
    }
    float s2 = red[0]; __syncthreads();
    float pf = __fdiv_rn(e2, s2);
    out[BATCH + b * CWIDTH + j] = pf;

    // ---- argmax(prob / q), first-index tie-break ----
    float q = qs[(long)b * VOCAB + idx];
    float ratio = __fdiv_rn(pf, q);
    red[j] = ratio; redi[j] = j;
    __syncthreads();
    for (int s = T2 / 2; s > 0; s >>= 1) {
        if (j < s) {
            float o = red[j + s]; int oi = redi[j + s];
            if (o > red[j] || (o == red[j] && oi < redi[j])) { red[j] = o; redi[j] = oi; }
        }
        __syncthreads();
    }

    if (j == 0) {
        float bvv = g_gval[b * NCHUNK]; int bii = g_gidx[b * NCHUNK];
        for (int c2 = 1; c2 < NCHUNK; ++c2) {
            float w = g_gval[b * NCHUNK + c2]; int wi = g_gidx[b * NCHUNK + c2];
            if (w > bvv || (w == bvv && wi < bii)) { bvv = w; bii = wi; }
        }
        int token = ix[redi[0]];
        float tmp = temperature[b];
        int samp = (tmp < 1e-5f) ? bii : token;
        out[b] = (float)samp;
    }
}

extern "C" void kernel_launch(void* const* d_in, const int* in_sizes, int n_in,
                              void* d_out, int out_size, void* d_ws, size_t ws_size,
                              hipStream_t stream) {
    const float* logits = (const float*)d_in[0];
    const float* temp   = (const float*)d_in[1];
    const int*   topk   = (const int*)d_in[2];
    const float* topp   = (const float*)d_in[3];
    const float* counts = (const float*)d_in[4];
    const void*  pmask  = d_in[5];
    const float* pres   = (const float*)d_in[6];
    const float* freq   = (const float*)d_in[7];
    const float* rep    = (const float*)d_in[8];
    const float* qs     = (const float*)d_in[9];
    float* out = (float*)d_out;

    float* g_topv = (float*)d_ws;                        // BATCH*CWIDTH
    int*   g_topi = (int*)(g_topv + BATCH * CWIDTH);     // BATCH*CWIDTH
    float* g_gval = (float*)(g_topi + BATCH * CWIDTH);   // BATCH*NCHUNK
    int*   g_gidx = (int*)(g_gval + BATCH * NCHUNK);     // BATCH*NCHUNK

    sampler_k1<<<BATCH * NCHUNK, T1, 0, stream>>>(
        logits, counts, pmask, temp, pres, freq, rep,
        g_topv, g_topi, g_gval, g_gidx);

    sampler_k2<<<BATCH, T2, 0, stream>>>(
        g_topv, g_topi, g_gval, g_gidx, temp, topk, topp, qs, out);
}